// Round 5
// baseline (265.332 us; speedup 1.0000x reference)
//
#include <hip/hip_runtime.h>
#include <hip/hip_fp16.h>

#define NN 50000
#define NE 800000
#define DD 128
#define NSTRIP 3125   // NN/16
#define NBUCK 196     // node>>8 buckets
#define MAXB 6144     // padded slot capacity per bucket (mean ~4480, 25 sigma margin)
#define ZROW NN       // dedicated zero row index in h1/h2 (sentinel slots)
#define NHIST 208     // histogram blocks

// workspace layout, element (4-byte word) offsets
#define OF_DINV  0            // float[NN]
#define OF_DEG   50000        // int[NN] in-degree (excl. self-loop)
#define OF_CUR   100000       // int[NN] scatter cursors
#define OF_OFFS2 150000       // int2[NN] (start, padded_end) into csru
#define OF_CSRU  250000       // ushort[196*MAXB] scattered src + ZROW sentinels
#define OF_H1    852112       // ushort[(NN+1)*DD] fp16 h1s = dinv*(x@W1)
#define OF_H2    4052176      // ushort[(NN+1)*DD] fp16 h2s = dinv*h2
#define OF_W1H   7252240      // ushort[16384] fragment order
#define OF_W1L   7260432
#define OF_W2H   7268624
#define OF_W2L   7276816      // end 7285008 words = 29.1 MB

typedef __attribute__((ext_vector_type(8))) short bf8_t;   // 8 bf16 = 4 VGPRs
typedef __attribute__((ext_vector_type(8))) unsigned short us8;
typedef __attribute__((ext_vector_type(4))) float f32x4;

static __device__ __forceinline__ unsigned short f2bf(float f) {
    unsigned int u = __float_as_uint(f);
    unsigned int r = (u + 0x7fffu + ((u >> 16) & 1u)) >> 16;   // RNE
    return (unsigned short)r;
}
static __device__ __forceinline__ float bf2f(unsigned short h) {
    return __uint_as_float(((unsigned int)h) << 16);
}
static __device__ __forceinline__ unsigned short f2h(float f) {
    return __half_as_ushort(__float2half(f));
}
static __device__ __forceinline__ float h2f(unsigned short u) {
    return __half2float(__ushort_as_half(u));
}

// L0: zero deg[] + the ZROW rows of h1/h2.
__global__ __launch_bounds__(256) void k_zero(int* __restrict__ deg,
                                              ushort* __restrict__ h1,
                                              ushort* __restrict__ h2) {
    int g = blockIdx.x * 256 + threadIdx.x;
    if (g < NN) deg[g] = 0;
    if (g < 64) ((unsigned int*)(h1 + (size_t)ZROW * DD))[g] = 0u;
    else if (g < 128) ((unsigned int*)(h2 + (size_t)ZROW * DD))[g - 64] = 0u;
}

// L1: blocks 0..15 = W split tables; blocks 16.. = global in-degree
// histogram (800k atomics on the L2-resident deg table; round-1 measured
// this pattern as near-free).
__global__ __launch_bounds__(256) void k_hw(
        const float* __restrict__ W1, const float* __restrict__ W2,
        ushort* __restrict__ w1h, ushort* __restrict__ w1l,
        ushort* __restrict__ w2h, ushort* __restrict__ w2l,
        const int* __restrict__ dst, int* __restrict__ deg) {
    int tid = threadIdx.x;
    if (blockIdx.x < 16) {
        int gg = blockIdx.x * 256 + tid;
        const float* W = (gg < 2048) ? W1 : W2;
        ushort* wh = (gg < 2048) ? w1h : w2h;
        ushort* wl = (gg < 2048) ? w1l : w2l;
        int g = gg & 2047;
        int ntile = g >> 8;
        int kk = (g >> 6) & 3;
        int lane = g & 63;
        int k0 = kk * 32 + ((lane >> 4) * 8);
        int col = ntile * 16 + (lane & 15);
#pragma unroll
        for (int j = 0; j < 8; ++j) {
            float w = W[(k0 + j) * DD + col];
            unsigned short h = f2bf(w);
            wh[(size_t)g * 8 + j] = h;
            wl[(size_t)g * 8 + j] = f2bf(w - bf2f(h));
        }
        return;
    }
    int g = (blockIdx.x - 16) * 256 + tid;
    for (int e = g; e < NE; e += NHIST * 256)
        atomicAdd(&deg[dst[e]], 1);
}

// L2: per-bucket scan of padded degrees -> offs2 (start, padded_end), dinv,
// scatter cursors, and ZROW sentinels in the per-node pad slots (<=3 each).
__global__ __launch_bounds__(256) void k_scan(const int* __restrict__ deg,
                                              int2* __restrict__ offs2,
                                              float* __restrict__ dinv,
                                              int* __restrict__ cur,
                                              ushort* __restrict__ csru) {
    __shared__ int sc[256];
    int b = blockIdx.x, tid = threadIdx.x;
    int node = b * 256 + tid;
    int dv = (node < NN) ? deg[node] : 0;
    int p = (dv + 3) & ~3;       // pad segment to multiple of 4
    sc[tid] = p;
    __syncthreads();
    for (int s = 1; s < 256; s <<= 1) {
        int t = (tid >= s) ? sc[tid - s] : 0;
        __syncthreads();
        sc[tid] += t;
        __syncthreads();
    }
    int start = b * MAXB + sc[tid] - p;
    if (node < NN) {
        offs2[node] = make_int2(start, start + p);
        dinv[node] = rsqrtf((float)(dv + 1));    // +1 self-loop
        cur[node] = start;
        for (int k = dv; k < p; ++k) csru[start + k] = (ushort)ZROW;
    }
}

// L3: blocks 0..195 = direct edge scatter via per-node atomic cursors
// (order within a node irrelevant);  blocks 196.. = layer-1 MFMA GEMM
// writing h1s = dinv[row]*(x@W1) in fp16 (deg complete after L1).
__global__ __launch_bounds__(256) void k_scg(
        const int* __restrict__ src, const int* __restrict__ dst,
        int* __restrict__ cur, ushort* __restrict__ csru,
        const int* __restrict__ deg,
        const float* __restrict__ X,
        const ushort* __restrict__ wh, const ushort* __restrict__ wl,
        ushort* __restrict__ H1) {
    int tid = threadIdx.x;
    if (blockIdx.x < 196) {
        int g = blockIdx.x * 256 + tid;
        for (int e = g; e < NE; e += 196 * 256) {
            int d = dst[e];
            int r = atomicAdd(&cur[d], 1);
            csru[r] = (ushort)src[e];
        }
        return;
    }
    // ---- GEMM half ----
    int wave = tid >> 6;
    int lane = tid & 63;
    int strip = (blockIdx.x - 196) * 4 + wave;
    if (strip >= NSTRIP) return;
    int rb = strip << 4;
    int m = lane & 15;
    int quad = lane >> 4;
    const float* ar = X + (size_t)(rb + m) * DD;
    f32x4 acc[8];
#pragma unroll
    for (int t = 0; t < 8; ++t) acc[t] = (f32x4){0.f, 0.f, 0.f, 0.f};
#pragma unroll
    for (int kk = 0; kk < 4; ++kk) {
        float4 xa = *(const float4*)(ar + kk * 32 + quad * 8);
        float4 xb = *(const float4*)(ar + kk * 32 + quad * 8 + 4);
        float xs[8] = {xa.x, xa.y, xa.z, xa.w, xb.x, xb.y, xb.z, xb.w};
        bf8_t ah, al;
#pragma unroll
        for (int j = 0; j < 8; ++j) {
            unsigned short hh = f2bf(xs[j]);
            ah[j] = (short)hh;
            al[j] = (short)f2bf(xs[j] - bf2f(hh));
        }
#pragma unroll
        for (int t = 0; t < 8; ++t) {
            size_t bo = ((size_t)(t * 4 + kk) * 64 + lane) * 8;
            bf8_t bh = *(const bf8_t*)(wh + bo);
            bf8_t bl = *(const bf8_t*)(wl + bo);
            acc[t] = __builtin_amdgcn_mfma_f32_16x16x32_bf16(ah, bh, acc[t], 0, 0, 0);
            acc[t] = __builtin_amdgcn_mfma_f32_16x16x32_bf16(ah, bl, acc[t], 0, 0, 0);
            acc[t] = __builtin_amdgcn_mfma_f32_16x16x32_bf16(al, bh, acc[t], 0, 0, 0);
        }
    }
    int4 dg = *(const int4*)(deg + rb + quad * 4);
    float dvv[4] = {rsqrtf((float)(dg.x + 1)), rsqrtf((float)(dg.y + 1)),
                    rsqrtf((float)(dg.z + 1)), rsqrtf((float)(dg.w + 1))};
    // C/D layout (m89-verified): col = lane&15, row = quad*4 + reg
#pragma unroll
    for (int t = 0; t < 8; ++t) {
#pragma unroll
        for (int r = 0; r < 4; ++r)
            H1[(size_t)(rb + quad * 4 + r) * DD + t * 16 + m] =
                f2h(dvv[r] * acc[t][r]);
    }
}

// FUSED layer-1 aggregation + layer-2 GEMM.  512 threads, one block = 16
// nodes.  Phase 1: 8 waves x 2 nodes; guarded 4-edge groups over the
// sentinel-padded segment (no per-lane masks; only ceil(deg/4) groups of
// VALU+loads executed, wave-uniform branches).
__global__ __launch_bounds__(512) void k_aggmm(const ushort* __restrict__ h1,
                                               const float* __restrict__ dinv,
                                               const int2* __restrict__ offs2,
                                               const ushort* __restrict__ csru,
                                               const float* __restrict__ b1,
                                               const ushort* __restrict__ w2h,
                                               const ushort* __restrict__ w2l,
                                               ushort* __restrict__ h2) {
    __shared__ float xs[16][136];
    int wave = threadIdx.x >> 6;
    int lane = threadIdx.x & 63;
    int rb = blockIdx.x * 16;
    int q = lane >> 4;
    int l = lane & 15;
    const float* bp = b1 + 8 * l;
    // ---- phase 1: 2 nodes per wave ----
    for (int nn = 0; nn < 2; ++nn) {
        int node = rb + wave * 2 + nn;
        int2 oe = offs2[node];
        int e1 = oe.y;               // padded end (multiple-of-4 segment)
        float a[8] = {0.f, 0.f, 0.f, 0.f, 0.f, 0.f, 0.f, 0.f};
        for (int eb = oe.x; eb < e1; eb += 32) {
            int rem = e1 - eb;       // uniform, multiple of 4
            us8 v[8];
#pragma unroll
            for (int j = 0; j < 8; ++j) {
                if (4 * j < rem) {
                    int s = (int)csru[eb + 4 * j + q];
                    v[j] = *(const us8*)(h1 + ((size_t)s << 7) + 8 * l);
                }
            }
#pragma unroll
            for (int j = 0; j < 8; ++j) {
                if (4 * j < rem) {
#pragma unroll
                    for (int d = 0; d < 8; ++d) a[d] += h2f(v[j][d]);
                }
            }
        }
        if (q == 0) {  // self-loop: + h1s[node] (pre-scaled)
            us8 v = *(const us8*)(h1 + ((size_t)node << 7) + 8 * l);
#pragma unroll
            for (int j = 0; j < 8; ++j) a[j] += h2f(v[j]);
        }
#pragma unroll
        for (int j = 0; j < 8; ++j) {
            a[j] += __shfl_xor(a[j], 16, 64);
            a[j] += __shfl_xor(a[j], 32, 64);
        }
        if (q == 0) {
            float dnode = dinv[node];
            float* xr = &xs[wave * 2 + nn][8 * l];
#pragma unroll
            for (int j = 0; j < 8; ++j)
                xr[j] = fmaxf(dnode * a[j] + bp[j], 0.f);
        }
    }
    __syncthreads();
    // ---- phase 2: each wave does N-tile t = wave; h2 stored PRE-SCALED ----
    int m = lane & 15;
    int quad = lane >> 4;
    int t = wave;
    f32x4 acc = (f32x4){0.f, 0.f, 0.f, 0.f};
#pragma unroll
    for (int kk = 0; kk < 4; ++kk) {
        const float* xr = &xs[m][kk * 32 + quad * 8];
        float4 xa = *(const float4*)xr;
        float4 xb = *(const float4*)(xr + 4);
        float xv[8] = {xa.x, xa.y, xa.z, xa.w, xb.x, xb.y, xb.z, xb.w};
        bf8_t ah, al;
#pragma unroll
        for (int j = 0; j < 8; ++j) {
            unsigned short hh = f2bf(xv[j]);
            ah[j] = (short)hh;
            al[j] = (short)f2bf(xv[j] - bf2f(hh));
        }
        size_t bo = ((size_t)(t * 4 + kk) * 64 + lane) * 8;
        bf8_t bh = *(const bf8_t*)(w2h + bo);
        bf8_t bl = *(const bf8_t*)(w2l + bo);
        acc = __builtin_amdgcn_mfma_f32_16x16x32_bf16(ah, bh, acc, 0, 0, 0);
        acc = __builtin_amdgcn_mfma_f32_16x16x32_bf16(ah, bl, acc, 0, 0, 0);
        acc = __builtin_amdgcn_mfma_f32_16x16x32_bf16(al, bh, acc, 0, 0, 0);
    }
    float4 dv4 = *(const float4*)(dinv + rb + quad * 4);
    float dvv[4] = {dv4.x, dv4.y, dv4.z, dv4.w};
#pragma unroll
    for (int r = 0; r < 4; ++r)
        h2[(size_t)(rb + quad * 4 + r) * DD + t * 16 + m] = f2h(dvv[r] * acc[r]);
}

// final aggregation over pre-scaled h2s: out[i] = relu(dinv_i*(sum h2s[s] +
// h2s[i]) + b2), guarded 4-edge groups as above.
__global__ __launch_bounds__(256) void k_agg(const ushort* __restrict__ h,
                                             const float* __restrict__ dinv,
                                             const int2* __restrict__ offs2,
                                             const ushort* __restrict__ csru,
                                             const float* __restrict__ bias,
                                             float* __restrict__ outf) {
    int wave = threadIdx.x >> 6;
    int lane = threadIdx.x & 63;
    int node = blockIdx.x * 4 + wave;   // grid = NN/4 exactly
    int q = lane >> 4;
    int l = lane & 15;
    int2 oe = offs2[node];
    int e1 = oe.y;                      // padded end
    float a[8] = {0.f, 0.f, 0.f, 0.f, 0.f, 0.f, 0.f, 0.f};
    for (int eb = oe.x; eb < e1; eb += 32) {
        int rem = e1 - eb;
        us8 v[8];
#pragma unroll
        for (int j = 0; j < 8; ++j) {
            if (4 * j < rem) {
                int s = (int)csru[eb + 4 * j + q];
                v[j] = *(const us8*)(h + ((size_t)s << 7) + 8 * l);
            }
        }
#pragma unroll
        for (int j = 0; j < 8; ++j) {
            if (4 * j < rem) {
#pragma unroll
                for (int d = 0; d < 8; ++d) a[d] += h2f(v[j][d]);
            }
        }
    }
    if (q == 0) {  // self-loop: + h2s[node]
        us8 v = *(const us8*)(h + ((size_t)node << 7) + 8 * l);
#pragma unroll
        for (int j = 0; j < 8; ++j) a[j] += h2f(v[j]);
    }
#pragma unroll
    for (int j = 0; j < 8; ++j) {
        a[j] += __shfl_xor(a[j], 16, 64);
        a[j] += __shfl_xor(a[j], 32, 64);
    }
    if (q == 0) {
        float dnode = dinv[node];
        float* op = outf + (size_t)node * DD + 8 * l;
        const float* bp = bias + 8 * l;
        float4 o0, o1;
        o0.x = fmaxf(dnode * a[0] + bp[0], 0.f);
        o0.y = fmaxf(dnode * a[1] + bp[1], 0.f);
        o0.z = fmaxf(dnode * a[2] + bp[2], 0.f);
        o0.w = fmaxf(dnode * a[3] + bp[3], 0.f);
        o1.x = fmaxf(dnode * a[4] + bp[4], 0.f);
        o1.y = fmaxf(dnode * a[5] + bp[5], 0.f);
        o1.z = fmaxf(dnode * a[6] + bp[6], 0.f);
        o1.w = fmaxf(dnode * a[7] + bp[7], 0.f);
        *(float4*)op = o0;
        *(float4*)(op + 4) = o1;
    }
}

extern "C" void kernel_launch(void* const* d_in, const int* in_sizes, int n_in,
                              void* d_out, int out_size, void* d_ws, size_t ws_size,
                              hipStream_t stream) {
    const float* x  = (const float*)d_in[0];
    const int*   ei = (const int*)d_in[1];
    const float* W1 = (const float*)d_in[2];
    const float* b1 = (const float*)d_in[3];
    const float* W2 = (const float*)d_in[4];
    const float* b2 = (const float*)d_in[5];
    float* out = (float*)d_out;

    const int* src = ei;        // edge_index[0]
    const int* dst = ei + NE;   // edge_index[1]

    int*    wsi  = (int*)d_ws;
    float*  wsf  = (float*)d_ws;
    ushort* wsu  = (ushort*)d_ws;
    float*  dinv  = wsf + OF_DINV;
    int*    deg   = wsi + OF_DEG;
    int*    cur   = wsi + OF_CUR;
    int2*   offs2 = (int2*)(wsi + OF_OFFS2);
    ushort* csru  = wsu + (size_t)OF_CSRU * 2;
    ushort* h1    = wsu + (size_t)OF_H1 * 2;
    ushort* h2    = wsu + (size_t)OF_H2 * 2;
    ushort* w1h   = wsu + (size_t)OF_W1H * 2;
    ushort* w1l   = wsu + (size_t)OF_W1L * 2;
    ushort* w2h   = wsu + (size_t)OF_W2H * 2;
    ushort* w2l   = wsu + (size_t)OF_W2L * 2;

    // 0: zero deg + zero rows (kernel, not memset — graph-capture safe)
    hipLaunchKernelGGL(k_zero, dim3(196), dim3(256), 0, stream, deg, h1, h2);
    // 1: wconv (16 blk) || in-degree histogram (208 blk)
    hipLaunchKernelGGL(k_hw, dim3(16 + NHIST), dim3(256), 0, stream,
                       W1, W2, w1h, w1l, w2h, w2l, dst, deg);
    // 2: per-bucket scan -> offs2/dinv/cursors + sentinels
    hipLaunchKernelGGL(k_scan, dim3(NBUCK), dim3(256), 0, stream,
                       deg, offs2, dinv, cur, csru);
    // 3: edge scatter (196 blk) || layer-1 GEMM -> pre-scaled fp16 h1s (782 blk)
    hipLaunchKernelGGL(k_scg, dim3(196 + (NSTRIP + 3) / 4), dim3(256), 0, stream,
                       src, dst, cur, csru, deg, x, w1h, w1l, h1);
    // 4: fused agg(L1)+relu+b1 -> @W2 -> pre-scaled fp16 h2s
    hipLaunchKernelGGL(k_aggmm, dim3(NSTRIP), dim3(512), 0, stream,
                       h1, dinv, offs2, csru, b1, w2h, w2l, h2);
    // 5: final aggregation -> out
    hipLaunchKernelGGL(k_agg, dim3(NN / 4), dim3(256), 0, stream,
                       h2, dinv, offs2, csru, b2, out);
}

// Round 6
// 250.672 us; speedup vs baseline: 1.0585x; 1.0585x over previous
//
#include <hip/hip_runtime.h>
#include <hip/hip_fp16.h>

#define NN 50000
#define NE 800000
#define DD 128
#define NSTRIP 3125   // NN/16
#define NB 196        // dst>>8 buckets (49999>>8 == 195)
#define CHUNK 4096    // edges per shuf block; 196 chunks
#define MAXB 6144     // bucket capacity (mean 4096, sigma ~64)
#define ZROW NN       // dedicated zero row index in h1/h2 (masked edge slots)

// workspace layout, element (4-byte word) offsets
#define OF_LCNT  0            // int[256*196] per-bucket-per-block counts, bucket-major
#define OF_LOFS  50176        // int[256*196] per-block local offsets, bucket-major
#define OF_DINV  100352       // float[NN]
#define OF_DEG   150352       // int[NN] in-degree (excl. self-loop)
#define OF_OFFS2 200352       // int2[NN] per-node (start,end) into padded csru
#define OF_TMP2  300352       // uint[196*CHUNK] block-major slabs, bucket-grouped
#define OF_CSRU  1103168      // ushort[196*MAXB] padded sorted src
#define OF_H1    1705280      // ushort[(NN+1)*DD] fp16 h1s = dinv*(x@W1)
#define OF_H2    4905344      // ushort[(NN+1)*DD] fp16 h2s = dinv*h2
#define OF_W1H   8105408      // ushort[16384] fragment order
#define OF_W1L   8113600
#define OF_W2H   8121792
#define OF_W2L   8129984      // end 8138176 words = 32.55 MB

typedef __attribute__((ext_vector_type(8))) short bf8_t;   // 8 bf16 = 4 VGPRs
typedef __attribute__((ext_vector_type(8))) unsigned short us8;
typedef __attribute__((ext_vector_type(4))) float f32x4;

static __device__ __forceinline__ unsigned short f2bf(float f) {
    unsigned int u = __float_as_uint(f);
    unsigned int r = (u + 0x7fffu + ((u >> 16) & 1u)) >> 16;   // RNE
    return (unsigned short)r;
}
static __device__ __forceinline__ float bf2f(unsigned short h) {
    return __uint_as_float(((unsigned int)h) << 16);
}
static __device__ __forceinline__ unsigned short f2h(float f) {
    return __half_as_ushort(__float2half(f));
}
static __device__ __forceinline__ float h2f(unsigned short u) {
    return __half2float(__ushort_as_half(u));
}

// L0: zero deg[] (atomic histogram target) + the ZROW rows of h1/h2.
__global__ __launch_bounds__(256) void k_zero(int* __restrict__ deg,
                                              ushort* __restrict__ h1,
                                              ushort* __restrict__ h2) {
    int g = blockIdx.x * 256 + threadIdx.x;
    if (g < NN) deg[g] = 0;
    if (g < 64) ((unsigned int*)(h1 + (size_t)ZROW * DD))[g] = 0u;
    else if (g < 128) ((unsigned int*)(h2 + (size_t)ZROW * DD))[g - 64] = 0u;
}

// L1: blocks 0..15 = W split tables; blocks 16..211 = cursor-free edge
// shuffle + global in-degree histogram (deg pre-zeroed by k_zero).
__global__ __launch_bounds__(256) void k_ws(
        const float* __restrict__ W1, const float* __restrict__ W2,
        ushort* __restrict__ w1h, ushort* __restrict__ w1l,
        ushort* __restrict__ w2h, ushort* __restrict__ w2l,
        const int* __restrict__ src, const int* __restrict__ dst,
        int* __restrict__ lcnt_g, int* __restrict__ lofs_g,
        unsigned int* __restrict__ tmp2, int* __restrict__ deg) {
    __shared__ int lcnt[256];
    __shared__ int lsc[256];
    __shared__ int lcur[256];
    int tid = threadIdx.x;
    if (blockIdx.x < 16) {
        // ---- weight conversion ----
        int gg = blockIdx.x * 256 + tid;
        const float* W = (gg < 2048) ? W1 : W2;
        ushort* wh = (gg < 2048) ? w1h : w2h;
        ushort* wl = (gg < 2048) ? w1l : w2l;
        int g = gg & 2047;
        int ntile = g >> 8;
        int kk = (g >> 6) & 3;
        int lane = g & 63;
        int k0 = kk * 32 + ((lane >> 4) * 8);
        int col = ntile * 16 + (lane & 15);
#pragma unroll
        for (int j = 0; j < 8; ++j) {
            float w = W[(k0 + j) * DD + col];
            unsigned short h = f2bf(w);
            wh[(size_t)g * 8 + j] = h;
            wl[(size_t)g * 8 + j] = f2bf(w - bf2f(h));
        }
        return;
    }
    // ---- edge shuffle ----
    int blk = blockIdx.x - 16;
    lcnt[tid] = 0;
    __syncthreads();
    int e0 = blk * CHUNK;
    int e1 = e0 + CHUNK; if (e1 > NE) e1 = NE;
    for (int e = e0 + tid; e < e1; e += 256) {
        int d = dst[e];
        atomicAdd(&lcnt[d >> 8], 1);
        atomicAdd(&deg[d], 1);          // global in-degree (round-1: ~free)
    }
    __syncthreads();
    int v = lcnt[tid];
    lsc[tid] = v;
    __syncthreads();
    for (int o = 1; o < 256; o <<= 1) {
        int t = (tid >= o) ? lsc[tid - o] : 0;
        __syncthreads();
        lsc[tid] += t;
        __syncthreads();
    }
    int excl = lsc[tid] - v;
    lcnt_g[tid * 196 + blk] = v;
    lofs_g[tid * 196 + blk] = excl;
    lcur[tid] = excl;
    __syncthreads();
    for (int e = e0 + tid; e < e1; e += 256) {
        int d = dst[e], s = src[e];
        int b = d >> 8;
        int r = atomicAdd(&lcur[b], 1);
        tmp2[blk * CHUNK + r] = ((unsigned int)s << 8) | (unsigned int)(d & 255);
    }
}

// L2: blocks 0..195 = per-bucket counting sort -> padded CSR (16-bit src) +
// offs2 + dinv;  blocks 196..977 = layer-1 MFMA GEMM writing h1s =
// dinv[row]*(x@W1) in fp16 (dinv recomputed from deg[] at C-write; deg is
// complete after L1, so no dependency on the co-running sort).
__global__ __launch_bounds__(256) void k_sg(
        const int* __restrict__ lcnt_g, const int* __restrict__ lofs_g,
        const unsigned int* __restrict__ tmp2, const int* __restrict__ deg,
        ushort* __restrict__ csru, int2* __restrict__ offs2,
        float* __restrict__ dinv,
        const float* __restrict__ X,
        const ushort* __restrict__ wh, const ushort* __restrict__ wl,
        ushort* __restrict__ H1) {
    __shared__ unsigned int ent[MAXB];
    __shared__ int c[256];
    __shared__ int p[256];
    __shared__ int o[256];
    __shared__ int cnt[256];
    __shared__ int boff[256];
    __shared__ int cur[256];
    int tid = threadIdx.x;
    if (blockIdx.x < 196) {
        int b = blockIdx.x;
        int cv = (tid < 196) ? lcnt_g[b * 196 + tid] : 0;
        o[tid] = (tid < 196) ? lofs_g[b * 196 + tid] : 0;
        c[tid] = cv;
        p[tid] = cv;
        cnt[tid] = 0;
        __syncthreads();
        for (int s = 1; s < 256; s <<= 1) {
            int t = (tid >= s) ? p[tid - s] : 0;
            __syncthreads();
            p[tid] += t;
            __syncthreads();
        }
        int nb = p[255];
        for (int i = tid; i < nb; i += 256) {
            int lo = 0, hi = 255;
#pragma unroll
            for (int it = 0; it < 8; ++it) {
                int mid = (lo + hi) >> 1;
                if (p[mid] > i) hi = mid; else lo = mid + 1;
            }
            int blk = lo;
            int j = i - (p[blk] - c[blk]);
            unsigned int e = tmp2[blk * CHUNK + o[blk] + j];
            ent[i] = e;
            atomicAdd(&cnt[e & 255], 1);
        }
        __syncthreads();
        int v = cnt[tid];
        boff[tid] = v;
        __syncthreads();
        for (int s = 1; s < 256; s <<= 1) {
            int t = (tid >= s) ? boff[tid - s] : 0;
            __syncthreads();
            boff[tid] += t;
            __syncthreads();
        }
        int excl = boff[tid] - v;
        int base = b * MAXB;
        int node = b * 256 + tid;
        if (node < NN) {
            offs2[node] = make_int2(base + excl, base + excl + v);
            dinv[node] = rsqrtf((float)(v + 1));   // +1 self-loop
        }
        cur[tid] = excl;
        __syncthreads();
        for (int i = tid; i < nb; i += 256) {
            unsigned int e = ent[i];
            int bin = e & 255;
            int r = atomicAdd(&cur[bin], 1);
            csru[base + r] = (ushort)(e >> 8);
        }
        return;
    }
    // ---- GEMM half ----
    int wave = tid >> 6;
    int lane = tid & 63;
    int strip = (blockIdx.x - 196) * 4 + wave;
    if (strip >= NSTRIP) return;
    int rb = strip << 4;
    int m = lane & 15;
    int quad = lane >> 4;
    const float* ar = X + (size_t)(rb + m) * DD;
    f32x4 acc[8];
#pragma unroll
    for (int t = 0; t < 8; ++t) acc[t] = (f32x4){0.f, 0.f, 0.f, 0.f};
#pragma unroll
    for (int kk = 0; kk < 4; ++kk) {
        float4 xa = *(const float4*)(ar + kk * 32 + quad * 8);
        float4 xb = *(const float4*)(ar + kk * 32 + quad * 8 + 4);
        float xs[8] = {xa.x, xa.y, xa.z, xa.w, xb.x, xb.y, xb.z, xb.w};
        bf8_t ah, al;
#pragma unroll
        for (int j = 0; j < 8; ++j) {
            unsigned short hh = f2bf(xs[j]);
            ah[j] = (short)hh;
            al[j] = (short)f2bf(xs[j] - bf2f(hh));
        }
#pragma unroll
        for (int t = 0; t < 8; ++t) {
            size_t bo = ((size_t)(t * 4 + kk) * 64 + lane) * 8;
            bf8_t bh = *(const bf8_t*)(wh + bo);
            bf8_t bl = *(const bf8_t*)(wl + bo);
            acc[t] = __builtin_amdgcn_mfma_f32_16x16x32_bf16(ah, bh, acc[t], 0, 0, 0);
            acc[t] = __builtin_amdgcn_mfma_f32_16x16x32_bf16(ah, bl, acc[t], 0, 0, 0);
            acc[t] = __builtin_amdgcn_mfma_f32_16x16x32_bf16(al, bh, acc[t], 0, 0, 0);
        }
    }
    // dinv for this thread's 4 output rows (deg complete after L1)
    int4 dg = *(const int4*)(deg + rb + quad * 4);
    float dvv[4] = {rsqrtf((float)(dg.x + 1)), rsqrtf((float)(dg.y + 1)),
                    rsqrtf((float)(dg.z + 1)), rsqrtf((float)(dg.w + 1))};
    // C/D layout (m89-verified): col = lane&15, row = quad*4 + reg
#pragma unroll
    for (int t = 0; t < 8; ++t) {
#pragma unroll
        for (int r = 0; r < 4; ++r)
            H1[(size_t)(rb + quad * 4 + r) * DD + t * 16 + m] =
                f2h(dvv[r] * acc[t][r]);
    }
}

// FUSED layer-1 aggregation + layer-2 GEMM.  512 threads, one block = 16
// nodes.  Phase 1: 8 waves x 2 nodes, DUAL-NODE interleaved rounds: both
// nodes' 8+8 row loads are issued before either is consumed -> 16 gathers
// in flight per wave (2x the MLP of the per-node loop).  Masked slots read
// the ZROW zero row (no per-lane guards on the load batch).
__global__ __launch_bounds__(512) void k_aggmm(const ushort* __restrict__ h1,
                                               const float* __restrict__ dinv,
                                               const int2* __restrict__ offs2,
                                               const ushort* __restrict__ csru,
                                               const float* __restrict__ b1,
                                               const ushort* __restrict__ w2h,
                                               const ushort* __restrict__ w2l,
                                               ushort* __restrict__ h2) {
    __shared__ float xs[16][136];
    int wave = threadIdx.x >> 6;
    int lane = threadIdx.x & 63;
    int rb = blockIdx.x * 16;
    int q = lane >> 4;
    int l = lane & 15;
    const float* bp = b1 + 8 * l;
    // ---- phase 1: dual-node interleaved gather ----
    int nodeA = rb + wave * 2;
    int nodeB = nodeA + 1;
    int2 oeA = offs2[nodeA];
    int2 oeB = offs2[nodeB];
    float aA[8] = {0.f, 0.f, 0.f, 0.f, 0.f, 0.f, 0.f, 0.f};
    float aB[8] = {0.f, 0.f, 0.f, 0.f, 0.f, 0.f, 0.f, 0.f};
    int ebA = oeA.x, ebB = oeB.x;
    while (ebA < oeA.y || ebB < oeB.y) {
        bool doA = (ebA < oeA.y), doB = (ebB < oeB.y);
        us8 vA[8], vB[8];
        if (doA) {
            int sA[8];
#pragma unroll
            for (int j = 0; j < 8; ++j) {
                int e = ebA + q + 4 * j;
                int er = (e < oeA.y) ? e : (oeA.y - 1);
                int sv = (int)csru[er];
                sA[j] = (e < oeA.y) ? sv : ZROW;
            }
#pragma unroll
            for (int j = 0; j < 8; ++j)
                vA[j] = *(const us8*)(h1 + ((size_t)sA[j] << 7) + 8 * l);
        }
        if (doB) {
            int sB[8];
#pragma unroll
            for (int j = 0; j < 8; ++j) {
                int e = ebB + q + 4 * j;
                int er = (e < oeB.y) ? e : (oeB.y - 1);
                int sv = (int)csru[er];
                sB[j] = (e < oeB.y) ? sv : ZROW;
            }
#pragma unroll
            for (int j = 0; j < 8; ++j)
                vB[j] = *(const us8*)(h1 + ((size_t)sB[j] << 7) + 8 * l);
        }
        if (doA) {
#pragma unroll
            for (int j = 0; j < 8; ++j) {
#pragma unroll
                for (int d = 0; d < 8; ++d) aA[d] += h2f(vA[j][d]);
            }
        }
        if (doB) {
#pragma unroll
            for (int j = 0; j < 8; ++j) {
#pragma unroll
                for (int d = 0; d < 8; ++d) aB[d] += h2f(vB[j][d]);
            }
        }
        ebA += 32; ebB += 32;
    }
    if (q == 0) {  // self-loops: + h1s[node] (pre-scaled)
        us8 v = *(const us8*)(h1 + ((size_t)nodeA << 7) + 8 * l);
        us8 u = *(const us8*)(h1 + ((size_t)nodeB << 7) + 8 * l);
#pragma unroll
        for (int j = 0; j < 8; ++j) { aA[j] += h2f(v[j]); aB[j] += h2f(u[j]); }
    }
#pragma unroll
    for (int j = 0; j < 8; ++j) {
        aA[j] += __shfl_xor(aA[j], 16, 64);
        aA[j] += __shfl_xor(aA[j], 32, 64);
        aB[j] += __shfl_xor(aB[j], 16, 64);
        aB[j] += __shfl_xor(aB[j], 32, 64);
    }
    if (q == 0) {
        float dA = dinv[nodeA], dB = dinv[nodeB];
        float* xrA = &xs[wave * 2][8 * l];
        float* xrB = &xs[wave * 2 + 1][8 * l];
#pragma unroll
        for (int j = 0; j < 8; ++j) {
            xrA[j] = fmaxf(dA * aA[j] + bp[j], 0.f);
            xrB[j] = fmaxf(dB * aB[j] + bp[j], 0.f);
        }
    }
    __syncthreads();
    // ---- phase 2: each wave does N-tile t = wave; h2 stored PRE-SCALED ----
    int m = lane & 15;
    int quad = lane >> 4;
    int t = wave;
    f32x4 acc = (f32x4){0.f, 0.f, 0.f, 0.f};
#pragma unroll
    for (int kk = 0; kk < 4; ++kk) {
        const float* xr = &xs[m][kk * 32 + quad * 8];
        float4 xa = *(const float4*)xr;
        float4 xb = *(const float4*)(xr + 4);
        float xv[8] = {xa.x, xa.y, xa.z, xa.w, xb.x, xb.y, xb.z, xb.w};
        bf8_t ah, al;
#pragma unroll
        for (int j = 0; j < 8; ++j) {
            unsigned short hh = f2bf(xv[j]);
            ah[j] = (short)hh;
            al[j] = (short)f2bf(xv[j] - bf2f(hh));
        }
        size_t bo = ((size_t)(t * 4 + kk) * 64 + lane) * 8;
        bf8_t bh = *(const bf8_t*)(w2h + bo);
        bf8_t bl = *(const bf8_t*)(w2l + bo);
        acc = __builtin_amdgcn_mfma_f32_16x16x32_bf16(ah, bh, acc, 0, 0, 0);
        acc = __builtin_amdgcn_mfma_f32_16x16x32_bf16(ah, bl, acc, 0, 0, 0);
        acc = __builtin_amdgcn_mfma_f32_16x16x32_bf16(al, bh, acc, 0, 0, 0);
    }
    float4 dv4 = *(const float4*)(dinv + rb + quad * 4);
    float dvv[4] = {dv4.x, dv4.y, dv4.z, dv4.w};
#pragma unroll
    for (int r = 0; r < 4; ++r)
        h2[(size_t)(rb + quad * 4 + r) * DD + t * 16 + m] = f2h(dvv[r] * acc[r]);
}

// final aggregation over pre-scaled h2s, dual-node interleaved (2 nodes per
// wave, 16 gathers in flight): out[i] = relu(dinv_i*(sum h2s[s] + h2s[i]) + b2)
__global__ __launch_bounds__(256) void k_agg(const ushort* __restrict__ h,
                                             const float* __restrict__ dinv,
                                             const int2* __restrict__ offs2,
                                             const ushort* __restrict__ csru,
                                             const float* __restrict__ bias,
                                             float* __restrict__ outf) {
    int wave = threadIdx.x >> 6;
    int lane = threadIdx.x & 63;
    int q = lane >> 4;
    int l = lane & 15;
    int nodeA = blockIdx.x * 8 + wave * 2;   // grid = NN/8 exactly
    int nodeB = nodeA + 1;
    int2 oeA = offs2[nodeA];
    int2 oeB = offs2[nodeB];
    float aA[8] = {0.f, 0.f, 0.f, 0.f, 0.f, 0.f, 0.f, 0.f};
    float aB[8] = {0.f, 0.f, 0.f, 0.f, 0.f, 0.f, 0.f, 0.f};
    int ebA = oeA.x, ebB = oeB.x;
    while (ebA < oeA.y || ebB < oeB.y) {
        bool doA = (ebA < oeA.y), doB = (ebB < oeB.y);
        us8 vA[8], vB[8];
        if (doA) {
            int sA[8];
#pragma unroll
            for (int j = 0; j < 8; ++j) {
                int e = ebA + q + 4 * j;
                int er = (e < oeA.y) ? e : (oeA.y - 1);
                int sv = (int)csru[er];
                sA[j] = (e < oeA.y) ? sv : ZROW;
            }
#pragma unroll
            for (int j = 0; j < 8; ++j)
                vA[j] = *(const us8*)(h + ((size_t)sA[j] << 7) + 8 * l);
        }
        if (doB) {
            int sB[8];
#pragma unroll
            for (int j = 0; j < 8; ++j) {
                int e = ebB + q + 4 * j;
                int er = (e < oeB.y) ? e : (oeB.y - 1);
                int sv = (int)csru[er];
                sB[j] = (e < oeB.y) ? sv : ZROW;
            }
#pragma unroll
            for (int j = 0; j < 8; ++j)
                vB[j] = *(const us8*)(h + ((size_t)sB[j] << 7) + 8 * l);
        }
        if (doA) {
#pragma unroll
            for (int j = 0; j < 8; ++j) {
#pragma unroll
                for (int d = 0; d < 8; ++d) aA[d] += h2f(vA[j][d]);
            }
        }
        if (doB) {
#pragma unroll
            for (int j = 0; j < 8; ++j) {
#pragma unroll
                for (int d = 0; d < 8; ++d) aB[d] += h2f(vB[j][d]);
            }
        }
        ebA += 32; ebB += 32;
    }
    if (q == 0) {  // self-loops
        us8 v = *(const us8*)(h + ((size_t)nodeA << 7) + 8 * l);
        us8 u = *(const us8*)(h + ((size_t)nodeB << 7) + 8 * l);
#pragma unroll
        for (int j = 0; j < 8; ++j) { aA[j] += h2f(v[j]); aB[j] += h2f(u[j]); }
    }
#pragma unroll
    for (int j = 0; j < 8; ++j) {
        aA[j] += __shfl_xor(aA[j], 16, 64);
        aA[j] += __shfl_xor(aA[j], 32, 64);
        aB[j] += __shfl_xor(aB[j], 16, 64);
        aB[j] += __shfl_xor(aB[j], 32, 64);
    }
    if (q == 0) {
        float dA = dinv[nodeA], dB = dinv[nodeB];
        const float* bp = bias + 8 * l;
        float* opA = outf + (size_t)nodeA * DD + 8 * l;
        float* opB = outf + (size_t)nodeB * DD + 8 * l;
        float4 o0, o1;
        o0.x = fmaxf(dA * aA[0] + bp[0], 0.f);
        o0.y = fmaxf(dA * aA[1] + bp[1], 0.f);
        o0.z = fmaxf(dA * aA[2] + bp[2], 0.f);
        o0.w = fmaxf(dA * aA[3] + bp[3], 0.f);
        o1.x = fmaxf(dA * aA[4] + bp[4], 0.f);
        o1.y = fmaxf(dA * aA[5] + bp[5], 0.f);
        o1.z = fmaxf(dA * aA[6] + bp[6], 0.f);
        o1.w = fmaxf(dA * aA[7] + bp[7], 0.f);
        *(float4*)opA = o0;
        *(float4*)(opA + 4) = o1;
        o0.x = fmaxf(dB * aB[0] + bp[0], 0.f);
        o0.y = fmaxf(dB * aB[1] + bp[1], 0.f);
        o0.z = fmaxf(dB * aB[2] + bp[2], 0.f);
        o0.w = fmaxf(dB * aB[3] + bp[3], 0.f);
        o1.x = fmaxf(dB * aB[4] + bp[4], 0.f);
        o1.y = fmaxf(dB * aB[5] + bp[5], 0.f);
        o1.z = fmaxf(dB * aB[6] + bp[6], 0.f);
        o1.w = fmaxf(dB * aB[7] + bp[7], 0.f);
        *(float4*)opB = o0;
        *(float4*)(opB + 4) = o1;
    }
}

extern "C" void kernel_launch(void* const* d_in, const int* in_sizes, int n_in,
                              void* d_out, int out_size, void* d_ws, size_t ws_size,
                              hipStream_t stream) {
    const float* x  = (const float*)d_in[0];
    const int*   ei = (const int*)d_in[1];
    const float* W1 = (const float*)d_in[2];
    const float* b1 = (const float*)d_in[3];
    const float* W2 = (const float*)d_in[4];
    const float* b2 = (const float*)d_in[5];
    float* out = (float*)d_out;

    const int* src = ei;        // edge_index[0]
    const int* dst = ei + NE;   // edge_index[1]

    int*          wsi  = (int*)d_ws;
    float*        wsf  = (float*)d_ws;
    ushort*       wsu  = (ushort*)d_ws;
    unsigned int* wsuw = (unsigned int*)d_ws;
    int*    lcnt_g = wsi + OF_LCNT;
    int*    lofs_g = wsi + OF_LOFS;
    float*  dinv   = wsf + OF_DINV;
    int*    deg    = wsi + OF_DEG;
    int2*   offs2  = (int2*)(wsi + OF_OFFS2);
    unsigned int* tmp2 = wsuw + OF_TMP2;
    ushort* csru   = wsu + (size_t)OF_CSRU * 2;
    ushort* h1     = wsu + (size_t)OF_H1 * 2;
    ushort* h2     = wsu + (size_t)OF_H2 * 2;
    ushort* w1h    = wsu + (size_t)OF_W1H * 2;
    ushort* w1l    = wsu + (size_t)OF_W1L * 2;
    ushort* w2h    = wsu + (size_t)OF_W2H * 2;
    ushort* w2l    = wsu + (size_t)OF_W2L * 2;

    // 0: zero deg + zero rows (kernel, not memset — graph-capture safe)
    hipLaunchKernelGGL(k_zero, dim3(196), dim3(256), 0, stream, deg, h1, h2);
    // 1: wconv (16 blk) || edge shuffle + deg histogram (196 blk)
    hipLaunchKernelGGL(k_ws, dim3(16 + 196), dim3(256), 0, stream,
                       W1, W2, w1h, w1l, w2h, w2l,
                       src, dst, lcnt_g, lofs_g, tmp2, deg);
    // 2: sort (196 blk) || layer-1 GEMM -> pre-scaled fp16 h1s (782 blk)
    hipLaunchKernelGGL(k_sg, dim3(196 + (NSTRIP + 3) / 4), dim3(256), 0, stream,
                       lcnt_g, lofs_g, tmp2, deg, csru, offs2, dinv,
                       x, w1h, w1l, h1);
    // 3: fused agg(L1)+relu+b1 -> @W2 -> pre-scaled fp16 h2s
    hipLaunchKernelGGL(k_aggmm, dim3(NSTRIP), dim3(512), 0, stream,
                       h1, dinv, offs2, csru, b1, w2h, w2l, h2);
    // 4: final aggregation -> out
    hipLaunchKernelGGL(k_agg, dim3(NN / 8), dim3(256), 0, stream,
                       h2, dinv, offs2, csru, b2, out);
}

// Round 7
// 222.960 us; speedup vs baseline: 1.1900x; 1.1243x over previous
//
#include <hip/hip_runtime.h>
#include <hip/hip_fp16.h>

#define NN 50000
#define NE 800000
#define DD 128
#define NSTRIP 3125   // NN/16
#define NB 196        // dst>>8 buckets (49999>>8 == 195)
#define CHUNK 4096    // edges per shuf block; 196 chunks
#define MAXB 6144     // bucket capacity (mean 4096, sigma ~64)
#define ZROW NN       // dedicated zero row index in h1/h2 (masked edge slots)

// workspace layout, element (4-byte word) offsets
#define OF_LCNT  0            // int[256*196] per-bucket-per-block counts, bucket-major
#define OF_LOFS  50176        // int[256*196] per-block local offsets, bucket-major
#define OF_DINV  100352       // float[NN]
#define OF_DEG   150352       // int[NN] in-degree (excl. self-loop)
#define OF_OFFS2 200352       // int2[NN] per-node (start,end) into padded csru
#define OF_TMP2  300352       // uint[196*CHUNK] block-major slabs, bucket-grouped
#define OF_CSRU  1103168      // ushort[196*MAXB] padded sorted src
#define OF_H1    1705280      // ushort[(NN+1)*DD] fp16 h1s = dinv*(x@W1)
#define OF_H2    4905344      // ushort[(NN+1)*DD] fp16 h2s = dinv*h2
#define OF_W1H   8105408      // ushort[16384] fragment order
#define OF_W1L   8113600
#define OF_W2H   8121792
#define OF_W2L   8129984      // end 8138176 words = 32.55 MB

typedef __attribute__((ext_vector_type(8))) short bf8_t;   // 8 bf16 = 4 VGPRs
typedef __attribute__((ext_vector_type(8))) unsigned short us8;
typedef __attribute__((ext_vector_type(4))) float f32x4;
typedef __attribute__((ext_vector_type(4))) unsigned int u32x4;

static __device__ __forceinline__ unsigned short f2bf(float f) {
    unsigned int u = __float_as_uint(f);
    unsigned int r = (u + 0x7fffu + ((u >> 16) & 1u)) >> 16;   // RNE
    return (unsigned short)r;
}
static __device__ __forceinline__ float bf2f(unsigned short h) {
    return __uint_as_float(((unsigned int)h) << 16);
}
static __device__ __forceinline__ unsigned short f2h(float f) {
    return __half_as_ushort(__float2half(f));
}
static __device__ __forceinline__ float h2f(unsigned short u) {
    return __half2float(__ushort_as_half(u));
}

// a[d] += f32(fp16 elem d of v), one v_fma_mix_f32 per element (vs
// cvt+add = 2 ops).  Bit-exact: fp16->f32 convert is exact, *1.0 exact,
// same f32 add order as before.
static __device__ __forceinline__ void acc_row(float a[8], us8 v) {
    u32x4 w = __builtin_bit_cast(u32x4, v);
#pragma unroll
    for (int k = 0; k < 4; ++k) {
        asm("v_fma_mix_f32 %0, %1, 1.0, %0 op_sel_hi:[1,0,0]"
            : "+v"(a[2 * k]) : "v"(w[k]));
        asm("v_fma_mix_f32 %0, %1, 1.0, %0 op_sel:[1,0,0] op_sel_hi:[1,0,0]"
            : "+v"(a[2 * k + 1]) : "v"(w[k]));
    }
}

// L0: zero deg[] (atomic histogram target) + the ZROW rows of h1/h2.
__global__ __launch_bounds__(256) void k_zero(int* __restrict__ deg,
                                              ushort* __restrict__ h1,
                                              ushort* __restrict__ h2) {
    int g = blockIdx.x * 256 + threadIdx.x;
    if (g < NN) deg[g] = 0;
    if (g < 64) ((unsigned int*)(h1 + (size_t)ZROW * DD))[g] = 0u;
    else if (g < 128) ((unsigned int*)(h2 + (size_t)ZROW * DD))[g - 64] = 0u;
}

// L1: blocks 0..15 = W split tables; blocks 16..211 = cursor-free edge
// shuffle + global in-degree histogram (deg pre-zeroed by k_zero).
__global__ __launch_bounds__(256) void k_ws(
        const float* __restrict__ W1, const float* __restrict__ W2,
        ushort* __restrict__ w1h, ushort* __restrict__ w1l,
        ushort* __restrict__ w2h, ushort* __restrict__ w2l,
        const int* __restrict__ src, const int* __restrict__ dst,
        int* __restrict__ lcnt_g, int* __restrict__ lofs_g,
        unsigned int* __restrict__ tmp2, int* __restrict__ deg) {
    __shared__ int lcnt[256];
    __shared__ int lsc[256];
    __shared__ int lcur[256];
    int tid = threadIdx.x;
    if (blockIdx.x < 16) {
        // ---- weight conversion ----
        int gg = blockIdx.x * 256 + tid;
        const float* W = (gg < 2048) ? W1 : W2;
        ushort* wh = (gg < 2048) ? w1h : w2h;
        ushort* wl = (gg < 2048) ? w1l : w2l;
        int g = gg & 2047;
        int ntile = g >> 8;
        int kk = (g >> 6) & 3;
        int lane = g & 63;
        int k0 = kk * 32 + ((lane >> 4) * 8);
        int col = ntile * 16 + (lane & 15);
#pragma unroll
        for (int j = 0; j < 8; ++j) {
            float w = W[(k0 + j) * DD + col];
            unsigned short h = f2bf(w);
            wh[(size_t)g * 8 + j] = h;
            wl[(size_t)g * 8 + j] = f2bf(w - bf2f(h));
        }
        return;
    }
    // ---- edge shuffle ----
    int blk = blockIdx.x - 16;
    lcnt[tid] = 0;
    __syncthreads();
    int e0 = blk * CHUNK;
    int e1 = e0 + CHUNK; if (e1 > NE) e1 = NE;
    for (int e = e0 + tid; e < e1; e += 256) {
        int d = dst[e];
        atomicAdd(&lcnt[d >> 8], 1);
        atomicAdd(&deg[d], 1);          // global in-degree (round-1: ~free)
    }
    __syncthreads();
    int v = lcnt[tid];
    lsc[tid] = v;
    __syncthreads();
    for (int o = 1; o < 256; o <<= 1) {
        int t = (tid >= o) ? lsc[tid - o] : 0;
        __syncthreads();
        lsc[tid] += t;
        __syncthreads();
    }
    int excl = lsc[tid] - v;
    lcnt_g[tid * 196 + blk] = v;
    lofs_g[tid * 196 + blk] = excl;
    lcur[tid] = excl;
    __syncthreads();
    for (int e = e0 + tid; e < e1; e += 256) {
        int d = dst[e], s = src[e];
        int b = d >> 8;
        int r = atomicAdd(&lcur[b], 1);
        tmp2[blk * CHUNK + r] = ((unsigned int)s << 8) | (unsigned int)(d & 255);
    }
}

// L2: blocks 0..195 = per-bucket counting sort -> padded CSR (16-bit src) +
// offs2 + dinv;  blocks 196..977 = layer-1 MFMA GEMM writing h1s =
// dinv[row]*(x@W1) in fp16 (dinv recomputed from deg[] at C-write; deg is
// complete after L1, so no dependency on the co-running sort).
__global__ __launch_bounds__(256) void k_sg(
        const int* __restrict__ lcnt_g, const int* __restrict__ lofs_g,
        const unsigned int* __restrict__ tmp2, const int* __restrict__ deg,
        ushort* __restrict__ csru, int2* __restrict__ offs2,
        float* __restrict__ dinv,
        const float* __restrict__ X,
        const ushort* __restrict__ wh, const ushort* __restrict__ wl,
        ushort* __restrict__ H1) {
    __shared__ unsigned int ent[MAXB];
    __shared__ int c[256];
    __shared__ int p[256];
    __shared__ int o[256];
    __shared__ int cnt[256];
    __shared__ int boff[256];
    __shared__ int cur[256];
    int tid = threadIdx.x;
    if (blockIdx.x < 196) {
        int b = blockIdx.x;
        int cv = (tid < 196) ? lcnt_g[b * 196 + tid] : 0;
        o[tid] = (tid < 196) ? lofs_g[b * 196 + tid] : 0;
        c[tid] = cv;
        p[tid] = cv;
        cnt[tid] = 0;
        __syncthreads();
        for (int s = 1; s < 256; s <<= 1) {
            int t = (tid >= s) ? p[tid - s] : 0;
            __syncthreads();
            p[tid] += t;
            __syncthreads();
        }
        int nb = p[255];
        for (int i = tid; i < nb; i += 256) {
            int lo = 0, hi = 255;
#pragma unroll
            for (int it = 0; it < 8; ++it) {
                int mid = (lo + hi) >> 1;
                if (p[mid] > i) hi = mid; else lo = mid + 1;
            }
            int blk = lo;
            int j = i - (p[blk] - c[blk]);
            unsigned int e = tmp2[blk * CHUNK + o[blk] + j];
            ent[i] = e;
            atomicAdd(&cnt[e & 255], 1);
        }
        __syncthreads();
        int v = cnt[tid];
        boff[tid] = v;
        __syncthreads();
        for (int s = 1; s < 256; s <<= 1) {
            int t = (tid >= s) ? boff[tid - s] : 0;
            __syncthreads();
            boff[tid] += t;
            __syncthreads();
        }
        int excl = boff[tid] - v;
        int base = b * MAXB;
        int node = b * 256 + tid;
        if (node < NN) {
            offs2[node] = make_int2(base + excl, base + excl + v);
            dinv[node] = rsqrtf((float)(v + 1));   // +1 self-loop
        }
        cur[tid] = excl;
        __syncthreads();
        for (int i = tid; i < nb; i += 256) {
            unsigned int e = ent[i];
            int bin = e & 255;
            int r = atomicAdd(&cur[bin], 1);
            csru[base + r] = (ushort)(e >> 8);
        }
        return;
    }
    // ---- GEMM half ----
    int wave = tid >> 6;
    int lane = tid & 63;
    int strip = (blockIdx.x - 196) * 4 + wave;
    if (strip >= NSTRIP) return;
    int rb = strip << 4;
    int m = lane & 15;
    int quad = lane >> 4;
    const float* ar = X + (size_t)(rb + m) * DD;
    f32x4 acc[8];
#pragma unroll
    for (int t = 0; t < 8; ++t) acc[t] = (f32x4){0.f, 0.f, 0.f, 0.f};
#pragma unroll
    for (int kk = 0; kk < 4; ++kk) {
        float4 xa = *(const float4*)(ar + kk * 32 + quad * 8);
        float4 xb = *(const float4*)(ar + kk * 32 + quad * 8 + 4);
        float xs[8] = {xa.x, xa.y, xa.z, xa.w, xb.x, xb.y, xb.z, xb.w};
        bf8_t ah, al;
#pragma unroll
        for (int j = 0; j < 8; ++j) {
            unsigned short hh = f2bf(xs[j]);
            ah[j] = (short)hh;
            al[j] = (short)f2bf(xs[j] - bf2f(hh));
        }
#pragma unroll
        for (int t = 0; t < 8; ++t) {
            size_t bo = ((size_t)(t * 4 + kk) * 64 + lane) * 8;
            bf8_t bh = *(const bf8_t*)(wh + bo);
            bf8_t bl = *(const bf8_t*)(wl + bo);
            acc[t] = __builtin_amdgcn_mfma_f32_16x16x32_bf16(ah, bh, acc[t], 0, 0, 0);
            acc[t] = __builtin_amdgcn_mfma_f32_16x16x32_bf16(ah, bl, acc[t], 0, 0, 0);
            acc[t] = __builtin_amdgcn_mfma_f32_16x16x32_bf16(al, bh, acc[t], 0, 0, 0);
        }
    }
    // dinv for this thread's 4 output rows (deg complete after L1)
    int4 dg = *(const int4*)(deg + rb + quad * 4);
    float dvv[4] = {rsqrtf((float)(dg.x + 1)), rsqrtf((float)(dg.y + 1)),
                    rsqrtf((float)(dg.z + 1)), rsqrtf((float)(dg.w + 1))};
    // C/D layout (m89-verified): col = lane&15, row = quad*4 + reg
#pragma unroll
    for (int t = 0; t < 8; ++t) {
#pragma unroll
        for (int r = 0; r < 4; ++r)
            H1[(size_t)(rb + quad * 4 + r) * DD + t * 16 + m] =
                f2h(dvv[r] * acc[t][r]);
    }
}

// FUSED layer-1 aggregation + layer-2 GEMM.  512 threads, one block = 16
// nodes.  Phase 1: 8 waves x 2 nodes; 32-edge masked rounds over PRE-SCALED
// fp16 rows -> pure unweighted row-sum; per-element accumulate is one
// v_fma_mix_f32 (masked slots read the ZROW zero row).
__global__ __launch_bounds__(512) void k_aggmm(const ushort* __restrict__ h1,
                                               const float* __restrict__ dinv,
                                               const int2* __restrict__ offs2,
                                               const ushort* __restrict__ csru,
                                               const float* __restrict__ b1,
                                               const ushort* __restrict__ w2h,
                                               const ushort* __restrict__ w2l,
                                               ushort* __restrict__ h2) {
    __shared__ float xs[16][136];
    int wave = threadIdx.x >> 6;
    int lane = threadIdx.x & 63;
    int rb = blockIdx.x * 16;
    int q = lane >> 4;
    int l = lane & 15;
    const float* bp = b1 + 8 * l;
    // ---- phase 1: 2 nodes per wave ----
    for (int nn = 0; nn < 2; ++nn) {
        int node = rb + wave * 2 + nn;
        int2 oe = offs2[node];
        int e1 = oe.y;
        float a[8] = {0.f, 0.f, 0.f, 0.f, 0.f, 0.f, 0.f, 0.f};
        for (int eb = oe.x; eb < e1; eb += 32) {
            int s[8];
#pragma unroll
            for (int j = 0; j < 8; ++j) {
                int e = eb + q + 4 * j;
                int er = (e < e1) ? e : (e1 - 1);
                er = (er < 0) ? 0 : er;
                int sv = (int)csru[er];
                s[j] = (e < e1) ? sv : ZROW;
            }
            us8 v[8];
#pragma unroll
            for (int j = 0; j < 8; ++j)
                v[j] = *(const us8*)(h1 + ((size_t)s[j] << 7) + 8 * l);
#pragma unroll
            for (int j = 0; j < 8; ++j) acc_row(a, v[j]);
        }
        if (q == 0) {  // self-loop: + h1s[node] (pre-scaled)
            us8 v = *(const us8*)(h1 + ((size_t)node << 7) + 8 * l);
            acc_row(a, v);
        }
#pragma unroll
        for (int j = 0; j < 8; ++j) {
            a[j] += __shfl_xor(a[j], 16, 64);
            a[j] += __shfl_xor(a[j], 32, 64);
        }
        if (q == 0) {
            float dnode = dinv[node];
            float* xr = &xs[wave * 2 + nn][8 * l];
#pragma unroll
            for (int j = 0; j < 8; ++j)
                xr[j] = fmaxf(dnode * a[j] + bp[j], 0.f);
        }
    }
    __syncthreads();
    // ---- phase 2: each wave does N-tile t = wave; h2 stored PRE-SCALED ----
    int m = lane & 15;
    int quad = lane >> 4;
    int t = wave;
    f32x4 acc = (f32x4){0.f, 0.f, 0.f, 0.f};
#pragma unroll
    for (int kk = 0; kk < 4; ++kk) {
        const float* xr = &xs[m][kk * 32 + quad * 8];
        float4 xa = *(const float4*)xr;
        float4 xb = *(const float4*)(xr + 4);
        float xv[8] = {xa.x, xa.y, xa.z, xa.w, xb.x, xb.y, xb.z, xb.w};
        bf8_t ah, al;
#pragma unroll
        for (int j = 0; j < 8; ++j) {
            unsigned short hh = f2bf(xv[j]);
            ah[j] = (short)hh;
            al[j] = (short)f2bf(xv[j] - bf2f(hh));
        }
        size_t bo = ((size_t)(t * 4 + kk) * 64 + lane) * 8;
        bf8_t bh = *(const bf8_t*)(w2h + bo);
        bf8_t bl = *(const bf8_t*)(w2l + bo);
        acc = __builtin_amdgcn_mfma_f32_16x16x32_bf16(ah, bh, acc, 0, 0, 0);
        acc = __builtin_amdgcn_mfma_f32_16x16x32_bf16(ah, bl, acc, 0, 0, 0);
        acc = __builtin_amdgcn_mfma_f32_16x16x32_bf16(al, bh, acc, 0, 0, 0);
    }
    float4 dv4 = *(const float4*)(dinv + rb + quad * 4);
    float dvv[4] = {dv4.x, dv4.y, dv4.z, dv4.w};
#pragma unroll
    for (int r = 0; r < 4; ++r)
        h2[(size_t)(rb + quad * 4 + r) * DD + t * 16 + m] = f2h(dvv[r] * acc[r]);
}

// final aggregation over pre-scaled h2s: out[i] = relu(dinv_i*(sum h2s[s] +
// h2s[i]) + b2)
__global__ __launch_bounds__(256) void k_agg(const ushort* __restrict__ h,
                                             const float* __restrict__ dinv,
                                             const int2* __restrict__ offs2,
                                             const ushort* __restrict__ csru,
                                             const float* __restrict__ bias,
                                             float* __restrict__ outf) {
    int wave = threadIdx.x >> 6;
    int lane = threadIdx.x & 63;
    int node = blockIdx.x * 4 + wave;   // grid = NN/4 exactly
    int q = lane >> 4;
    int l = lane & 15;
    int2 oe = offs2[node];
    int e1 = oe.y;
    float a[8] = {0.f, 0.f, 0.f, 0.f, 0.f, 0.f, 0.f, 0.f};
    for (int eb = oe.x; eb < e1; eb += 32) {
        int s[8];
#pragma unroll
        for (int j = 0; j < 8; ++j) {
            int e = eb + q + 4 * j;
            int er = (e < e1) ? e : (e1 - 1);
            er = (er < 0) ? 0 : er;
            int sv = (int)csru[er];
            s[j] = (e < e1) ? sv : ZROW;
        }
        us8 v[8];
#pragma unroll
        for (int j = 0; j < 8; ++j)
            v[j] = *(const us8*)(h + ((size_t)s[j] << 7) + 8 * l);
#pragma unroll
        for (int j = 0; j < 8; ++j) acc_row(a, v[j]);
    }
    if (q == 0) {  // self-loop: + h2s[node]
        us8 v = *(const us8*)(h + ((size_t)node << 7) + 8 * l);
        acc_row(a, v);
    }
#pragma unroll
    for (int j = 0; j < 8; ++j) {
        a[j] += __shfl_xor(a[j], 16, 64);
        a[j] += __shfl_xor(a[j], 32, 64);
    }
    if (q == 0) {
        float dnode = dinv[node];
        float* op = outf + (size_t)node * DD + 8 * l;
        const float* bp = bias + 8 * l;
        float4 o0, o1;
        o0.x = fmaxf(dnode * a[0] + bp[0], 0.f);
        o0.y = fmaxf(dnode * a[1] + bp[1], 0.f);
        o0.z = fmaxf(dnode * a[2] + bp[2], 0.f);
        o0.w = fmaxf(dnode * a[3] + bp[3], 0.f);
        o1.x = fmaxf(dnode * a[4] + bp[4], 0.f);
        o1.y = fmaxf(dnode * a[5] + bp[5], 0.f);
        o1.z = fmaxf(dnode * a[6] + bp[6], 0.f);
        o1.w = fmaxf(dnode * a[7] + bp[7], 0.f);
        *(float4*)op = o0;
        *(float4*)(op + 4) = o1;
    }
}

extern "C" void kernel_launch(void* const* d_in, const int* in_sizes, int n_in,
                              void* d_out, int out_size, void* d_ws, size_t ws_size,
                              hipStream_t stream) {
    const float* x  = (const float*)d_in[0];
    const int*   ei = (const int*)d_in[1];
    const float* W1 = (const float*)d_in[2];
    const float* b1 = (const float*)d_in[3];
    const float* W2 = (const float*)d_in[4];
    const float* b2 = (const float*)d_in[5];
    float* out = (float*)d_out;

    const int* src = ei;        // edge_index[0]
    const int* dst = ei + NE;   // edge_index[1]

    int*          wsi  = (int*)d_ws;
    float*        wsf  = (float*)d_ws;
    ushort*       wsu  = (ushort*)d_ws;
    unsigned int* wsuw = (unsigned int*)d_ws;
    int*    lcnt_g = wsi + OF_LCNT;
    int*    lofs_g = wsi + OF_LOFS;
    float*  dinv   = wsf + OF_DINV;
    int*    deg    = wsi + OF_DEG;
    int2*   offs2  = (int2*)(wsi + OF_OFFS2);
    unsigned int* tmp2 = wsuw + OF_TMP2;
    ushort* csru   = wsu + (size_t)OF_CSRU * 2;
    ushort* h1     = wsu + (size_t)OF_H1 * 2;
    ushort* h2     = wsu + (size_t)OF_H2 * 2;
    ushort* w1h    = wsu + (size_t)OF_W1H * 2;
    ushort* w1l    = wsu + (size_t)OF_W1L * 2;
    ushort* w2h    = wsu + (size_t)OF_W2H * 2;
    ushort* w2l    = wsu + (size_t)OF_W2L * 2;

    // 0: zero deg + zero rows (kernel, not memset — graph-capture safe)
    hipLaunchKernelGGL(k_zero, dim3(196), dim3(256), 0, stream, deg, h1, h2);
    // 1: wconv (16 blk) || edge shuffle + deg histogram (196 blk)
    hipLaunchKernelGGL(k_ws, dim3(16 + 196), dim3(256), 0, stream,
                       W1, W2, w1h, w1l, w2h, w2l,
                       src, dst, lcnt_g, lofs_g, tmp2, deg);
    // 2: sort (196 blk) || layer-1 GEMM -> pre-scaled fp16 h1s (782 blk)
    hipLaunchKernelGGL(k_sg, dim3(196 + (NSTRIP + 3) / 4), dim3(256), 0, stream,
                       lcnt_g, lofs_g, tmp2, deg, csru, offs2, dinv,
                       x, w1h, w1l, h1);
    // 3: fused agg(L1)+relu+b1 -> @W2 -> pre-scaled fp16 h2s
    hipLaunchKernelGGL(k_aggmm, dim3(NSTRIP), dim3(512), 0, stream,
                       h1, dinv, offs2, csru, b1, w2h, w2l, h2);
    // 4: final aggregation -> out
    hipLaunchKernelGGL(k_agg, dim3(NN / 4), dim3(256), 0, stream,
                       h2, dinv, offs2, csru, b2, out);
}